// Round 9
// baseline (101.787 us; speedup 1.0000x reference)
//
#include <hip/hip_runtime.h>

#define N_PTS 16384
#define M_CENT 2048
#define MAXS 64
#define NCELL 1000      // 10x10x10 per batch
#define RSAFE 0.201f
#define R2C 0.04f
#define QG 4            // centroids per query block (one wave each)

// ---- workspace layout (byte offsets into d_ws) ----
// hist   @ 0      : B*1000 u32
// off    @ 16384  : B*1000+1 u32
// cursor @ 32768  : B*1000 u32
// sidx   @ 65536  : B*16384 int   (local point index 0..16383)
// spts   @ 327680 : B*16384 float4 (x,y,z,|p|^2)

__global__ void hist_kernel(const float* __restrict__ pcs,
                            unsigned* __restrict__ hist, int npts_total) {
#pragma clang fp contract(off)
    const int i = blockIdx.x * 256 + threadIdx.x;
    if (i >= npts_total) return;
    const float* p = pcs + (size_t)i * 3;
    const float x = p[0], y = p[1], z = p[2];
    int ix = (int)(x * 10.0f); ix = ix > 9 ? 9 : (ix < 0 ? 0 : ix);
    int iy = (int)(y * 10.0f); iy = iy > 9 ? 9 : (iy < 0 ? 0 : iy);
    int iz = (int)(z * 10.0f); iz = iz > 9 ? 9 : (iz < 0 ? 0 : iz);
    const int b = i >> 14;
    atomicAdd(&hist[b * NCELL + ix * 100 + iy * 10 + iz], 1u);
}

__global__ __launch_bounds__(1024) void scan_kernel(
    const unsigned* __restrict__ hist, unsigned* __restrict__ off,
    unsigned* __restrict__ cursor, int tc) {
    __shared__ unsigned s[1024];
    const int t = threadIdx.x;
    unsigned v[4]; unsigned sum = 0;
#pragma unroll
    for (int j = 0; j < 4; ++j) {
        const int id = 4 * t + j;
        v[j] = (id < tc) ? hist[id] : 0u;
        sum += v[j];
    }
    s[t] = sum;
    __syncthreads();
    for (int d = 1; d < 1024; d <<= 1) {
        const unsigned a = (t >= d) ? s[t - d] : 0u;
        __syncthreads();
        s[t] += a;
        __syncthreads();
    }
    unsigned run = s[t] - sum;   // exclusive prefix
#pragma unroll
    for (int j = 0; j < 4; ++j) {
        const int id = 4 * t + j;
        if (id < tc) { off[id] = run; cursor[id] = run; run += v[j]; }
    }
    if (t == 1023) off[tc] = s[1023];   // total
}

__global__ void scatter_kernel(const float* __restrict__ pcs,
                               unsigned* __restrict__ cursor,
                               float4* __restrict__ spts,
                               int* __restrict__ sidx, int npts_total) {
#pragma clang fp contract(off)
    const int i = blockIdx.x * 256 + threadIdx.x;
    if (i >= npts_total) return;
    const float* p = pcs + (size_t)i * 3;
    const float x = p[0], y = p[1], z = p[2];
    float p2 = x * x; p2 += y * y; p2 += z * z;   // same order as reference
    int ix = (int)(x * 10.0f); ix = ix > 9 ? 9 : (ix < 0 ? 0 : ix);
    int iy = (int)(y * 10.0f); iy = iy > 9 ? 9 : (iy < 0 ? 0 : iy);
    int iz = (int)(z * 10.0f); iz = iz > 9 ? 9 : (iz < 0 ? 0 : iz);
    const int b = i >> 14;
    const unsigned pos = atomicAdd(&cursor[b * NCELL + ix * 100 + iy * 10 + iz], 1u);
    spts[pos] = make_float4(x, y, z, p2);
    sidx[pos] = i & (N_PTS - 1);
}

// 2048 blocks x 256 threads; wave w handles centroid blockIdx.x*4+w alone.
// No __syncthreads: all LDS state is wave-private (wave-ordered LDS ops).
__global__ __launch_bounds__(256) void query_kernel(
    const float* __restrict__ cent, const float4* __restrict__ spts,
    const int* __restrict__ sidx, const unsigned* __restrict__ off,
    int* __restrict__ out) {
#pragma clang fp contract(off)
    __shared__ unsigned bm[QG][N_PTS / 32];   // 8 KB bitmaps
    __shared__ int slots[QG][MAXS];           // 1 KB

    const int lane = threadIdx.x & 63;
    const int wid  = threadIdx.x >> 6;
    const int cg   = blockIdx.x * QG + wid;
    const int b    = cg >> 11;

    const float* cp = cent + (size_t)cg * 3;
    const float cx = cp[0], cy = cp[1], cz = cp[2];
    float c2 = cx * cx; c2 += cy * cy; c2 += cz * cz;

    // zero this wave's bitmap (8 words/lane)
#pragma unroll
    for (int w = 0; w < 8; ++w) bm[wid][w * 64 + lane] = 0u;

    // cell box covering all possible computed-hits
    int ix0 = (int)floorf((cx - RSAFE) * 10.0f); ix0 = ix0 < 0 ? 0 : ix0;
    int ix1 = (int)floorf((cx + RSAFE) * 10.0f); ix1 = ix1 > 9 ? 9 : ix1;
    int iy0 = (int)floorf((cy - RSAFE) * 10.0f); iy0 = iy0 < 0 ? 0 : iy0;
    int iy1 = (int)floorf((cy + RSAFE) * 10.0f); iy1 = iy1 > 9 ? 9 : iy1;
    int iz0 = (int)floorf((cz - RSAFE) * 10.0f); iz0 = iz0 < 0 ? 0 : iz0;
    int iz1 = (int)floorf((cz + RSAFE) * 10.0f); iz1 = iz1 > 9 ? 9 : iz1;

    const unsigned* offb = off + b * NCELL;
    for (int ix = ix0; ix <= ix1; ++ix) {
        for (int iy = iy0; iy <= iy1; ++iy) {
            const int cbase = ix * 100 + iy * 10;
            const unsigned s0 = offb[cbase + iz0];
            const unsigned s1 = offb[cbase + iz1 + 1];   // iz-contiguous segment
            for (unsigned j = s0 + lane; j < s1; j += 64) {
                const float4 pt = spts[j];
                float cr = cx * pt.x; cr += cy * pt.y; cr += cz * pt.z;
                const float d2 = (c2 + pt.w) - 2.0f * cr;
                if (d2 <= R2C) {
                    const int li = sidx[j];
                    atomicOr(&bm[wid][li >> 5], 1u << (li & 31));
                }
            }
        }
    }

    // select the 64 lowest set bits (exact ascending order)
    unsigned w8[8]; unsigned pc = 0;
#pragma unroll
    for (int k = 0; k < 8; ++k) {
        w8[k] = bm[wid][8 * lane + k];
        pc += __popc(w8[k]);
    }
    unsigned inc = pc;
#pragma unroll
    for (int d = 1; d < 64; d <<= 1) {
        const unsigned t = __shfl_up(inc, d);
        if (lane >= d) inc += t;
    }
    const unsigned total = __shfl(inc, 63);
    unsigned run = inc - pc;    // exclusive prefix of hits before this lane's words
    if (run < MAXS && pc > 0) {
#pragma unroll
        for (int k = 0; k < 8; ++k) {
            unsigned bits = w8[k];
            const int base = (8 * lane + k) << 5;
            while (bits && run < MAXS) {
                const int bit = __ffs(bits) - 1;
                bits &= bits - 1;
                slots[wid][run++] = base + bit;
            }
            if (run >= MAXS) break;
        }
    }

    const int cnt = (int)(total < MAXS ? total : MAXS);
    int val;
    if (cnt == 0) {
        val = N_PTS;
    } else {
        val = (lane < cnt) ? slots[wid][lane] : slots[wid][0];
    }
    out[((size_t)cg << 6) + lane] = val;
}

extern "C" void kernel_launch(void* const* d_in, const int* in_sizes, int n_in,
                              void* d_out, int out_size, void* d_ws, size_t ws_size,
                              hipStream_t stream) {
    const float* pcs  = (const float*)d_in[0];
    const float* cent = (const float*)d_in[1];
    int* out = (int*)d_out;

    const int B = in_sizes[0] / (N_PTS * 3);     // 4
    const int npts_total = B * N_PTS;            // 65536
    const int tc = B * NCELL;                    // 4000

    char* ws = (char*)d_ws;
    unsigned* hist   = (unsigned*)(ws + 0);
    unsigned* off    = (unsigned*)(ws + 16384);
    unsigned* cursor = (unsigned*)(ws + 32768);
    int*      sidx   = (int*)     (ws + 65536);
    float4*   spts   = (float4*)  (ws + 327680);

    hipMemsetAsync(hist, 0, (size_t)tc * sizeof(unsigned), stream);
    hist_kernel<<<(npts_total + 255) / 256, 256, 0, stream>>>(pcs, hist, npts_total);
    scan_kernel<<<1, 1024, 0, stream>>>(hist, off, cursor, tc);
    scatter_kernel<<<(npts_total + 255) / 256, 256, 0, stream>>>(pcs, cursor, spts, sidx, npts_total);
    query_kernel<<<B * M_CENT / QG, 256, 0, stream>>>(cent, spts, sidx, off, out);
}